// Round 12
// baseline (112.871 us; speedup 1.0000x reference)
//
#include <hip/hip_runtime.h>
#include <hip/hip_bf16.h>

typedef __attribute__((ext_vector_type(4))) float  f32x4;
typedef __attribute__((ext_vector_type(8))) short  bf16x8;
typedef __attribute__((ext_vector_type(4))) short  bf16x4v;

#define EPAD 68   // f32 elems per epilogue LDS row
#define AS1 __attribute__((address_space(1)))
#define AS3 __attribute__((address_space(3)))

__device__ __forceinline__ unsigned short f2bf(float f) {
  __hip_bfloat16 h = __float2bfloat16(f);
  unsigned short u; __builtin_memcpy(&u, &h, 2); return u;
}
__device__ __forceinline__ float bf2f(short u) {
  unsigned int w = ((unsigned int)(unsigned short)u) << 16;
  float f; __builtin_memcpy(&f, &w, 4); return f;
}

// Fully-inline sincos. k in f32 (|x|<=~6 -> k exact), reduction in f64
// (tan pole needs ABSOLUTE reduced-arg err < ~6e-9), polys f32.
__device__ __forceinline__ void my_sincos(float xf, float& s_out, float& c_out) {
  const float kf = __builtin_rintf(xf * 0.636619772367581343f);      // x * 2/pi
  const int   q  = (int)kf;
  const double kd = (double)kf;
  double rd = __builtin_fma(-kd, 1.5707963267948966,    (double)xf); // pio2_hi
  rd        = __builtin_fma(-kd, 6.123233995736766e-17, rd);         // pio2_lo
  const float r = (float)rd;
  const float z = r * r;
  const float ps = fmaf(z, fmaf(z, fmaf(z, 2.7183114939898219e-06f,
                                           -1.9839334836096632e-04f),
                                   8.3333293858894632e-03f),
                        -1.6666666641626524e-01f);
  const float sr = fmaf(r * z, ps, r);                               // sin(r)
  const float pc = fmaf(z, fmaf(z, fmaf(z, 2.4390448796277409e-05f,
                                           -1.3886763774609929e-03f),
                                   4.1666623323739063e-02f),
                        -4.9999999725103100e-01f);
  const float cr = fmaf(z, pc, 1.0f);                                // cos(r)
  const bool swap = (q & 1) != 0;
  float s1 = swap ? cr : sr;
  float c1 = swap ? sr : cr;
  if (q & 2)       s1 = -s1;
  if ((q + 1) & 2) c1 = -c1;
  s_out = s1; c_out = c1;
}

// ---- fused prep: blocks 0..255 transpose W -> Wt(bf16); blocks 256+ stream
// x -> xb(bf16) and g = b*sin(x)+c*cos(x)+d*tan(x) -> bf16 (trig hides under
// the memory-bound stream; measured at the BW floor ~22 us).
__global__ __launch_bounds__(256)
void prep_all(const float* __restrict__ W, const float* __restrict__ x,
              const float* __restrict__ bv, const float* __restrict__ cv,
              const float* __restrict__ dv,
              unsigned short* __restrict__ Wt, unsigned short* __restrict__ xb,
              unsigned short* __restrict__ g, int H, int n4) {
  __shared__ float tile[64][65];
  const int t = threadIdx.x;
  if (blockIdx.x < 256) {
    const int blk = blockIdx.x;
    const int n0 = (blk & 15) << 6;
    const int k0 = (blk >> 4) << 6;
    #pragma unroll
    for (int it = 0; it < 4; ++it) {
      int q = it * 256 + t;
      int r = q >> 4, c4 = (q & 15) << 2;
      f32x4 v = *(const f32x4*)&W[(size_t)(k0 + r) * H + n0 + c4];
      tile[r][c4 + 0] = v[0]; tile[r][c4 + 1] = v[1];
      tile[r][c4 + 2] = v[2]; tile[r][c4 + 3] = v[3];
    }
    __syncthreads();
    #pragma unroll
    for (int it = 0; it < 4; ++it) {
      int q = it * 256 + t;
      int r = q >> 4, c4 = (q & 15) << 2;
      bf16x4v o;
      #pragma unroll
      for (int j = 0; j < 4; ++j) o[j] = (short)f2bf(tile[c4 + j][r]);
      *(bf16x4v*)&Wt[(size_t)(n0 + r) * H + k0 + c4] = o;
    }
  } else {
    const int jm = (H >> 2) - 1;             // H pow2: chunk-index mask
    int i = (blockIdx.x - 256) * 256 + t;
    const int stride = ((int)gridDim.x - 256) * 256;
    for (; i < n4; i += stride) {
      f32x4 v = ((const f32x4*)x)[i];
      const int j4 = (i & jm) << 2;
      f32x4 b4 = *(const f32x4*)&bv[j4];
      f32x4 c4 = *(const f32x4*)&cv[j4];
      f32x4 d4 = *(const f32x4*)&dv[j4];
      bf16x4v xo, go;
      #pragma unroll
      for (int e = 0; e < 4; ++e) {
        xo[e] = (short)f2bf(v[e]);
        float s, co;
        my_sincos(v[e], s, co);
        const float tn = s * __builtin_amdgcn_rcpf(co);  // |err| ~0.13 @ pole
        go[e] = (short)f2bf(fmaf(b4[e], s, fmaf(c4[e], co, d4[e] * tn)));
      }
      ((bf16x4v*)xb)[i] = xo;
      ((bf16x4v*)g)[i]  = go;
    }
  }
}

// ---- fallback prep kernels ----
__global__ __launch_bounds__(256)
void transpose_W(const float* __restrict__ W, unsigned short* __restrict__ Wt, int H) {
  __shared__ float tile[64][65];
  const int k0 = blockIdx.y * 64;
  const int n0 = blockIdx.x * 64;
  const int t = threadIdx.x;
  #pragma unroll
  for (int it = 0; it < 4; ++it) {
    int q = it * 256 + t;
    int r = q >> 4, c4 = (q & 15) << 2;
    f32x4 v = *(const f32x4*)&W[(size_t)(k0 + r) * H + n0 + c4];
    tile[r][c4 + 0] = v[0]; tile[r][c4 + 1] = v[1];
    tile[r][c4 + 2] = v[2]; tile[r][c4 + 3] = v[3];
  }
  __syncthreads();
  #pragma unroll
  for (int it = 0; it < 4; ++it) {
    int q = it * 256 + t;
    int r = q >> 4, c4 = (q & 15) << 2;
    bf16x4v o;
    #pragma unroll
    for (int j = 0; j < 4; ++j) o[j] = (short)f2bf(tile[c4 + j][r]);
    *(bf16x4v*)&Wt[(size_t)(n0 + r) * H + k0 + c4] = o;
  }
}
__global__ __launch_bounds__(256)
void cvt_x(const float* __restrict__ x, unsigned short* __restrict__ xb, int n4) {
  int i = blockIdx.x * 256 + threadIdx.x;
  const int stride = gridDim.x * 256;
  for (; i < n4; i += stride) {
    f32x4 v = ((const f32x4*)x)[i];
    bf16x4v o;
    #pragma unroll
    for (int j = 0; j < 4; ++j) o[j] = (short)f2bf(v[j]);
    ((bf16x4v*)xb)[i] = o;
  }
}

// ---- main GEMM: W-panel-resident, ZERO barriers in the K-loop ----
// Block = 256(M) x 64(N), 8 waves x 512 threads, wave owns 32 rows x 64 cols.
// The block's entire Wt panel (64 cols x K) sits in LDS in two 64KB halves
// (16 K-tiles of [64][32] bf16, 4KB each, r10-verified XOR swizzle:
//   phys = (R>>1)*128 + ((4*(R&1)+lq) ^ ((R>>1)&7))*16  -> 2 lanes/bank).
// Staged by global_load_lds with LINEAR dest + inverse-swizzled global src
// (rule #21). A-fragments are loaded per-wave DIRECTLY from global xb into
// VGPRs (L2/L3-resident; no LDS, no cross-wave hazard). Result: the K-loop
// has no __syncthreads at all -- rounds 6-11 showed every barrier-per-step
// structure converges to ~64us while no pipe exceeds ~27us; the convoy was
// the cost. 3 barriers total (post-stage x2, pre-epilogue). 64KB LDS ->
// 2 blocks/CU; grid 1024 -> 2 rounds (epilogue/K-loop cross-block overlap).
__global__ __launch_bounds__(512, 4)
void gemm_wres(const unsigned short* __restrict__ xb,
               const unsigned short* __restrict__ Wt,
               const unsigned short* __restrict__ g,
               float* __restrict__ out, float S, int H) {
  __shared__ unsigned char smem[65536];
  float* Es = (float*)smem;                         // epilogue overlay (34.8KB)

  const int tid  = threadIdx.x;
  const int nwg  = gridDim.x;
  // XCD swizzle (nwg % 8 == 0): per XCD, consecutive works span all 16 bj
  // (full 2MB Wt L2-resident) with bi shared in runs of 16 (xb panel reuse).
  const int work = (blockIdx.x & 7) * (nwg >> 3) + (blockIdx.x >> 3);
  const int bj   = work & 15;                       // 1024/64  = 16 N tiles
  const int bi   = work >> 4;                       // 16384/256 = 64 M tiles
  const int i0   = bi * 256, j0 = bj * 64;
  const int wave = tid >> 6, lane = tid & 63;
  const int l16  = lane & 15, lq = lane >> 4;

  // ---- staging map (constant per thread): dest D = issue*8192 + tid*16.
  // kt = D>>12 = issue*2 + (tid>>8); d = (tid&255)*16; sup=d>>7=t8>>3;
  // slotL = (t8&7)^(sup&7); row = sup*2+(slotL>>2); col8 = (slotL&3)*8.
  const int t8    = tid & 255;
  const int sup   = t8 >> 3;
  const int slotL = (t8 & 7) ^ (sup & 7);
  const int srow  = sup * 2 + (slotL >> 2);
  const int scol  = (slotL & 3) << 3;
  const unsigned short* sP = &Wt[(size_t)(j0 + srow) * H + (tid >> 8) * 32 + scol];

  #define STAGEH(h)                                                            \
    do {                                                                       \
      _Pragma("unroll")                                                        \
      for (int is = 0; is < 8; ++is)                                           \
        __builtin_amdgcn_global_load_lds(                                      \
          (const AS1 void*)(sP + (h) * 512 + is * 64),                         \
          (AS3 void*)((char*)smem + is * 8192 + tid * 16), 16, 0, 0);          \
    } while (0)

  // B-fragment LDS byte offsets within a K-tile (r10-verified, conflict-free)
  int bOff[4];
  #pragma unroll
  for (int ni = 0; ni < 4; ++ni) {
    const int R = ni * 16 + l16;
    bOff[ni] = (R >> 1) * 128 + ((4 * (R & 1) + lq) ^ ((R >> 1) & 7)) * 16;
  }
  // A-fragment global bases (direct-to-VGPR; 16 rows x 64B segments, L2/L3)
  const unsigned short* aB0 = &xb[(size_t)(i0 + wave * 32 +  0 + l16) * H + lq * 8];
  const unsigned short* aB1 = &xb[(size_t)(i0 + wave * 32 + 16 + l16) * H + lq * 8];

  f32x4 acc[2][4] = {};

  STAGEH(0);
  __syncthreads();                                  // half-0 landed
  #pragma unroll 4
  for (int kt = 0; kt < 16; ++kt) {                 // NO barriers in here
    const int ko = kt * 32;
    bf16x8 a0 = *(const bf16x8*)(aB0 + ko);
    bf16x8 a1 = *(const bf16x8*)(aB1 + ko);
    const char* tb = (const char*)smem + kt * 4096;
    #pragma unroll
    for (int ni = 0; ni < 4; ++ni) {
      bf16x8 bf = *(const bf16x8*)(tb + bOff[ni]);
      acc[0][ni] = __builtin_amdgcn_mfma_f32_16x16x32_bf16(a0, bf, acc[0][ni], 0, 0, 0);
      acc[1][ni] = __builtin_amdgcn_mfma_f32_16x16x32_bf16(a1, bf, acc[1][ni], 0, 0, 0);
    }
  }
  __syncthreads();                                  // all waves done with half-0
  STAGEH(1);
  __syncthreads();                                  // half-1 landed
  #pragma unroll 4
  for (int kt = 0; kt < 16; ++kt) {
    const int ko = 512 + kt * 32;
    bf16x8 a0 = *(const bf16x8*)(aB0 + ko);
    bf16x8 a1 = *(const bf16x8*)(aB1 + ko);
    const char* tb = (const char*)smem + kt * 4096;
    #pragma unroll
    for (int ni = 0; ni < 4; ++ni) {
      bf16x8 bf = *(const bf16x8*)(tb + bOff[ni]);
      acc[0][ni] = __builtin_amdgcn_mfma_f32_16x16x32_bf16(a0, bf, acc[0][ni], 0, 0, 0);
      acc[1][ni] = __builtin_amdgcn_mfma_f32_16x16x32_bf16(a1, bf, acc[1][ni], 0, 0, 0);
    }
  }
  __syncthreads();                                  // before Es overlays panel
  #undef STAGEH

  // ---- epilogue: per-wave LDS transpose then coalesced f32x4 IO ----
  // C/D fragment layout: col = l16, row = lq*4 + r  [m89-verified]
  float* ep = Es + wave * (16 * EPAD);
  const int rr = lane >> 2;           // 0..15
  const int cq = (lane & 3) * 16;     // 0,16,32,48
  #pragma unroll
  for (int mi = 0; mi < 2; ++mi) {
    #pragma unroll
    for (int ni = 0; ni < 4; ++ni)
      #pragma unroll
      for (int r = 0; r < 4; ++r)
        ep[(lq * 4 + r) * EPAD + ni * 16 + l16] = acc[mi][ni][r];
    // same-wave ds_write -> ds_read: in-order LDS pipe, compiler waits lgkmcnt.
    const int i  = i0 + wave * 32 + mi * 16 + rr;
    const int jb = j0 + cq;
    float* orow = &out[(size_t)i * H + jb];
    const unsigned short* grow = &g[(size_t)i * H + jb];
    #pragma unroll
    for (int t = 0; t < 4; ++t) {
      f32x4 a = *(const f32x4*)&ep[rr * EPAD + cq + 4 * t];
      bf16x4v gv = *(const bf16x4v*)&grow[4 * t];
      f32x4 o;
      #pragma unroll
      for (int e = 0; e < 4; ++e) o[e] = S * (a[e] + bf2f(gv[e]));
      *(f32x4*)&orow[4 * t] = o;
    }
  }
}

// ---- fallback GEMM (round-6 structure, 256 thr) for small-ws / odd-shape ----
template <int MODE>   // 1: xb staging + trig epi ; 2: f32 staging + trig epi
__global__ __launch_bounds__(256, 2)
void gemm_fb(const float* __restrict__ x, const unsigned short* __restrict__ xb,
             const unsigned short* __restrict__ Wt,
             const float* __restrict__ bv, const float* __restrict__ cv,
             const float* __restrict__ dv, float* __restrict__ out,
             float S, int H) {
  __shared__ unsigned char smem[36864];
  unsigned short* As = (unsigned short*)smem;            // [128][72]
  unsigned short* Bs = As + 128 * 72;
  float*          Es = (float*)smem;

  const int tid  = threadIdx.x;
  const int nwg  = gridDim.x;
  const int work = (nwg % 8 == 0) ? (blockIdx.x & 7) * (nwg >> 3) + (blockIdx.x >> 3)
                                  : blockIdx.x;
  const int nbj  = H / 128;
  const int bj   = work % nbj;
  const int bi   = work / nbj;
  const int i0   = bi * 128, j0 = bj * 128;
  const int wave = tid >> 6, lane = tid & 63;
  const int wr = wave >> 1, wc = wave & 1;
  const int l16 = lane & 15, lq = lane >> 4;

  f32x4 acc[4][4] = {};
  for (int kk = 0; kk < H; kk += 64) {
    if constexpr (MODE == 1) {
      #pragma unroll
      for (int it = 0; it < 4; ++it) {
        int q = it * 256 + tid;
        int r = q >> 3, c8 = (q & 7) << 3;
        *(bf16x8*)&As[r * 72 + c8] = *(const bf16x8*)&xb[(size_t)(i0 + r) * H + kk + c8];
      }
    } else {
      #pragma unroll
      for (int it = 0; it < 8; ++it) {
        int q = it * 256 + tid;
        int r = q >> 4, c4 = (q & 15) << 2;
        f32x4 v = *(const f32x4*)&x[(size_t)(i0 + r) * H + kk + c4];
        bf16x4v o;
        #pragma unroll
        for (int j = 0; j < 4; ++j) o[j] = (short)f2bf(v[j]);
        *(bf16x4v*)&As[r * 72 + c4] = o;
      }
    }
    #pragma unroll
    for (int it = 0; it < 4; ++it) {
      int q = it * 256 + tid;
      int r = q >> 3, c8 = (q & 7) << 3;
      *(bf16x8*)&Bs[r * 72 + c8] = *(const bf16x8*)&Wt[(size_t)(j0 + r) * H + kk + c8];
    }
    __syncthreads();
    #pragma unroll
    for (int s = 0; s < 2; ++s) {
      bf16x8 af[4], bfr[4];
      #pragma unroll
      for (int mi = 0; mi < 4; ++mi)
        af[mi] = *(const bf16x8*)&As[(wr * 64 + mi * 16 + l16) * 72 + s * 32 + lq * 8];
      #pragma unroll
      for (int ni = 0; ni < 4; ++ni)
        bfr[ni] = *(const bf16x8*)&Bs[(wc * 64 + ni * 16 + l16) * 72 + s * 32 + lq * 8];
      #pragma unroll
      for (int mi = 0; mi < 4; ++mi)
        #pragma unroll
        for (int ni = 0; ni < 4; ++ni)
          acc[mi][ni] = __builtin_amdgcn_mfma_f32_16x16x32_bf16(af[mi], bfr[ni], acc[mi][ni], 0, 0, 0);
    }
    __syncthreads();
  }
  float* ep = Es + wave * (16 * EPAD);
  const int rr = lane >> 2;
  const int cq = (lane & 3) * 16;
  #pragma unroll
  for (int mi = 0; mi < 4; ++mi) {
    #pragma unroll
    for (int ni = 0; ni < 4; ++ni)
      #pragma unroll
      for (int r = 0; r < 4; ++r)
        ep[(lq * 4 + r) * EPAD + ni * 16 + l16] = acc[mi][ni][r];
    const int i  = i0 + wr * 64 + mi * 16 + rr;
    const int jb = j0 + wc * 64 + cq;
    const float* xrow = &x[(size_t)i * H + jb];
    float*       orow = &out[(size_t)i * H + jb];
    #pragma unroll
    for (int t = 0; t < 4; ++t) {
      f32x4 a  = *(const f32x4*)&ep[rr * EPAD + cq + 4 * t];
      f32x4 xv = *(const f32x4*)&xrow[4 * t];
      f32x4 b4 = *(const f32x4*)&bv[jb + 4 * t];
      f32x4 c4 = *(const f32x4*)&cv[jb + 4 * t];
      f32x4 d4 = *(const f32x4*)&dv[jb + 4 * t];
      f32x4 o;
      #pragma unroll
      for (int e = 0; e < 4; ++e) {
        float s, co;
        my_sincos(xv[e], s, co);
        const float tanv = s * __builtin_amdgcn_rcpf(co);
        o[e] = S * (fmaf(b4[e], s, a[e]) + fmaf(c4[e], co, d4[e] * tanv));
      }
      *(f32x4*)&orow[4 * t] = o;
    }
  }
}

extern "C" void kernel_launch(void* const* d_in, const int* in_sizes, int n_in,
                              void* d_out, int out_size, void* d_ws, size_t ws_size,
                              hipStream_t stream) {
  const float* x = (const float*)d_in[0];
  const float* W = (const float*)d_in[1];
  const float* b = (const float*)d_in[2];
  const float* c = (const float*)d_in[3];
  const float* d = (const float*)d_in[4];
  float* out = (float*)d_out;
  const int H = in_sizes[2];          // 1024
  const int M = in_sizes[0] / H;      // 16384

  // Scalar RK4 factor: y_final = S * z (ODE linear in y, y0 = 0).
  const int NT = 100;
  float ts[NT];
  const float step = (float)(1.0 / 99.0);
  for (int i = 0; i < NT; ++i) ts[i] = (float)i * step;
  ts[NT - 1] = 1.0f;
  double yy = 0.0;
  for (int i = 0; i < NT - 1; ++i) {
    const double t = (double)ts[i], dt = (double)(ts[i + 1] - ts[i]);
    const double k1 = t - yy;
    const double k2 = (t + 0.5 * dt) - (yy + 0.5 * dt * k1);
    const double k3 = (t + 0.5 * dt) - (yy + 0.5 * dt * k2);
    const double k4 = (t + dt) - (yy + dt * k3);
    yy += dt / 6.0 * (k1 + 2.0 * k2 + 2.0 * k3 + k4);
  }
  const float S = (float)yy;

  unsigned short* Wt = (unsigned short*)d_ws;                 // 2 MB bf16 W^T
  unsigned short* xb = Wt + (size_t)H * H;                    // 32 MB bf16 x
  unsigned short* g  = xb + (size_t)M * H;                    // 32 MB bf16 g
  const size_t needW  = (size_t)H * H * 2;
  const size_t needXb = (size_t)M * H * 2;
  const int n4 = M * H / 4;

  const bool shapeOK = (H == 1024) && (M % 256 == 0) && ((M / 256) * 16 % 8 == 0);

  if (ws_size >= needW + 2 * needXb && shapeOK) {
    prep_all<<<256 + 2048, 256, 0, stream>>>(W, x, b, c, d, Wt, xb, g, H, n4);
    const int nblk = (M / 256) * 16;                          // 1024
    gemm_wres<<<nblk, 512, 0, stream>>>(xb, Wt, g, out, S, H);
  } else if (ws_size >= needW + needXb) {
    dim3 tgrid(H / 64, H / 64);
    transpose_W<<<tgrid, 256, 0, stream>>>(W, Wt, H);
    cvt_x<<<2048, 256, 0, stream>>>(x, xb, n4);
    gemm_fb<1><<<(H / 128) * (M / 128), 256, 0, stream>>>(x, xb, Wt, b, c, d, out, S, H);
  } else {
    dim3 tgrid(H / 64, H / 64);
    transpose_W<<<tgrid, 256, 0, stream>>>(W, Wt, H);
    gemm_fb<2><<<(H / 128) * (M / 128), 256, 0, stream>>>(x, nullptr, Wt, b, c, d, out, S, H);
  }
}

// Round 13
// 81.835 us; speedup vs baseline: 1.3793x; 1.3793x over previous
//
#include <hip/hip_runtime.h>
#include <hip/hip_bf16.h>

typedef __attribute__((ext_vector_type(4))) float  f32x4;
typedef __attribute__((ext_vector_type(8))) short  bf16x8;
typedef __attribute__((ext_vector_type(4))) short  bf16x4v;

#define EPAD 68   // f32 elems per epilogue LDS row
#define AS1 __attribute__((address_space(1)))
#define AS3 __attribute__((address_space(3)))

__device__ __forceinline__ unsigned short f2bf(float f) {
  __hip_bfloat16 h = __float2bfloat16(f);
  unsigned short u; __builtin_memcpy(&u, &h, 2); return u;
}
__device__ __forceinline__ float bf2f(short u) {
  unsigned int w = ((unsigned int)(unsigned short)u) << 16;
  float f; __builtin_memcpy(&f, &w, 4); return f;
}

// Fully-inline sincos. k in f32 (|x|<=~6 -> k exact), reduction in f64
// (tan pole needs ABSOLUTE reduced-arg err < ~6e-9), polys f32.
__device__ __forceinline__ void my_sincos(float xf, float& s_out, float& c_out) {
  const float kf = __builtin_rintf(xf * 0.636619772367581343f);      // x * 2/pi
  const int   q  = (int)kf;
  const double kd = (double)kf;
  double rd = __builtin_fma(-kd, 1.5707963267948966,    (double)xf); // pio2_hi
  rd        = __builtin_fma(-kd, 6.123233995736766e-17, rd);         // pio2_lo
  const float r = (float)rd;
  const float z = r * r;
  const float ps = fmaf(z, fmaf(z, fmaf(z, 2.7183114939898219e-06f,
                                           -1.9839334836096632e-04f),
                                   8.3333293858894632e-03f),
                        -1.6666666641626524e-01f);
  const float sr = fmaf(r * z, ps, r);                               // sin(r)
  const float pc = fmaf(z, fmaf(z, fmaf(z, 2.4390448796277409e-05f,
                                           -1.3886763774609929e-03f),
                                   4.1666623323739063e-02f),
                        -4.9999999725103100e-01f);
  const float cr = fmaf(z, pc, 1.0f);                                // cos(r)
  const bool swap = (q & 1) != 0;
  float s1 = swap ? cr : sr;
  float c1 = swap ? sr : cr;
  if (q & 2)       s1 = -s1;
  if ((q + 1) & 2) c1 = -c1;
  s_out = s1; c_out = c1;
}

// ---- fused prep: blocks 0..255 transpose W -> Wt(bf16); blocks 256+ stream
// x -> xb(bf16) and g = b*sin(x)+c*cos(x)+d*tan(x) -> bf16 (trig hides under
// the memory-bound stream; measured at the BW floor ~22 us).
__global__ __launch_bounds__(256)
void prep_all(const float* __restrict__ W, const float* __restrict__ x,
              const float* __restrict__ bv, const float* __restrict__ cv,
              const float* __restrict__ dv,
              unsigned short* __restrict__ Wt, unsigned short* __restrict__ xb,
              unsigned short* __restrict__ g, int H, int n4) {
  __shared__ float tile[64][65];
  const int t = threadIdx.x;
  if (blockIdx.x < 256) {
    const int blk = blockIdx.x;
    const int n0 = (blk & 15) << 6;
    const int k0 = (blk >> 4) << 6;
    #pragma unroll
    for (int it = 0; it < 4; ++it) {
      int q = it * 256 + t;
      int r = q >> 4, c4 = (q & 15) << 2;
      f32x4 v = *(const f32x4*)&W[(size_t)(k0 + r) * H + n0 + c4];
      tile[r][c4 + 0] = v[0]; tile[r][c4 + 1] = v[1];
      tile[r][c4 + 2] = v[2]; tile[r][c4 + 3] = v[3];
    }
    __syncthreads();
    #pragma unroll
    for (int it = 0; it < 4; ++it) {
      int q = it * 256 + t;
      int r = q >> 4, c4 = (q & 15) << 2;
      bf16x4v o;
      #pragma unroll
      for (int j = 0; j < 4; ++j) o[j] = (short)f2bf(tile[c4 + j][r]);
      *(bf16x4v*)&Wt[(size_t)(n0 + r) * H + k0 + c4] = o;
    }
  } else {
    const int jm = (H >> 2) - 1;             // H pow2: chunk-index mask
    int i = (blockIdx.x - 256) * 256 + t;
    const int stride = ((int)gridDim.x - 256) * 256;
    for (; i < n4; i += stride) {
      f32x4 v = ((const f32x4*)x)[i];
      const int j4 = (i & jm) << 2;
      f32x4 b4 = *(const f32x4*)&bv[j4];
      f32x4 c4 = *(const f32x4*)&cv[j4];
      f32x4 d4 = *(const f32x4*)&dv[j4];
      bf16x4v xo, go;
      #pragma unroll
      for (int e = 0; e < 4; ++e) {
        xo[e] = (short)f2bf(v[e]);
        float s, co;
        my_sincos(v[e], s, co);
        const float tn = s * __builtin_amdgcn_rcpf(co);  // |err| ~0.13 @ pole
        go[e] = (short)f2bf(fmaf(b4[e], s, fmaf(c4[e], co, d4[e] * tn)));
      }
      ((bf16x4v*)xb)[i] = xo;
      ((bf16x4v*)g)[i]  = go;
    }
  }
}

// ---- fallback prep kernels ----
__global__ __launch_bounds__(256)
void transpose_W(const float* __restrict__ W, unsigned short* __restrict__ Wt, int H) {
  __shared__ float tile[64][65];
  const int k0 = blockIdx.y * 64;
  const int n0 = blockIdx.x * 64;
  const int t = threadIdx.x;
  #pragma unroll
  for (int it = 0; it < 4; ++it) {
    int q = it * 256 + t;
    int r = q >> 4, c4 = (q & 15) << 2;
    f32x4 v = *(const f32x4*)&W[(size_t)(k0 + r) * H + n0 + c4];
    tile[r][c4 + 0] = v[0]; tile[r][c4 + 1] = v[1];
    tile[r][c4 + 2] = v[2]; tile[r][c4 + 3] = v[3];
  }
  __syncthreads();
  #pragma unroll
  for (int it = 0; it < 4; ++it) {
    int q = it * 256 + t;
    int r = q >> 4, c4 = (q & 15) << 2;
    bf16x4v o;
    #pragma unroll
    for (int j = 0; j < 4; ++j) o[j] = (short)f2bf(tile[c4 + j][r]);
    *(bf16x4v*)&Wt[(size_t)(n0 + r) * H + k0 + c4] = o;
  }
}
__global__ __launch_bounds__(256)
void cvt_x(const float* __restrict__ x, unsigned short* __restrict__ xb, int n4) {
  int i = blockIdx.x * 256 + threadIdx.x;
  const int stride = gridDim.x * 256;
  for (; i < n4; i += stride) {
    f32x4 v = ((const f32x4*)x)[i];
    bf16x4v o;
    #pragma unroll
    for (int j = 0; j < 4; ++j) o[j] = (short)f2bf(v[j]);
    ((bf16x4v*)xb)[i] = o;
  }
}

// ---- main GEMM: 256x256 tile, 8 waves, r10-proven schedule ----
// Rationale (r13): staged L2/L3 traffic scales as M*K*(N/BN) + N*K*(M/BM):
// 512MB @128^2 -> 192MB @256^2 (-62%); LDS-read redundancy drops; each CU
// runs ONE 8-wave convoy instead of four in-phase 4-wave convoys (fewer,
// fatter barrier periods). Schedule is exactly r10's (verified): dbuf
// global_load_lds BK=32, stage(t+1) issued before compute(t), one
// __syncthreads per step; XOR swizzle (verified bank-conflict-free and
// bijective in r10) with linear LDS dest + inverse-swizzled global source.
// Buffers: buf s at smem+s*32768; A [256][32]sw 16KB at +0, B 16KB at +16384.
__global__ __launch_bounds__(512, 2)
void gemm_256(const unsigned short* __restrict__ xb,
              const unsigned short* __restrict__ Wt,
              const unsigned short* __restrict__ g,
              float* __restrict__ out, float S, int H) {
  __shared__ unsigned char smem[65536];
  float* Es = (float*)smem;                         // epilogue overlay (34.8KB)

  const int tid  = threadIdx.x;
  const int nwg  = gridDim.x;
  const int work = (blockIdx.x & 7) * (nwg >> 3) + (blockIdx.x >> 3);
  const int nbj  = H >> 8;                          // N tiles of 256
  const int bj   = work % nbj;
  const int bi   = work / nbj;
  const int i0   = bi * 256, j0 = bj * 256;
  const int wave = tid >> 6, lane = tid & 63;
  const int wr   = wave >> 2, wc = wave & 3;        // 2(M) x 4(N) wave grid
  const int l16  = lane & 15, lq = lane >> 4;

  // Staging sources (inverse swizzle; r10-verified map). Thread issues 2 A
  // chunks + 2 B chunks of 16B: dest D = is*8192 + tid*16 within the region.
  const unsigned short *aS0, *aS1, *bS0, *bS1;
  {
    const int D0 = tid * 16,        sup0 = D0 >> 7;
    const int sl0 = ((D0 >> 4) & 7) ^ (sup0 & 7);
    const int r0  = sup0 * 2 + (sl0 >> 2), c0 = (sl0 & 3) << 3;
    const int D1 = 8192 + tid * 16, sup1 = D1 >> 7;
    const int sl1 = ((D1 >> 4) & 7) ^ (sup1 & 7);
    const int r1  = sup1 * 2 + (sl1 >> 2), c1 = (sl1 & 3) << 3;
    aS0 = &xb[(size_t)(i0 + r0) * H + c0];
    aS1 = &xb[(size_t)(i0 + r1) * H + c1];
    bS0 = &Wt[(size_t)(j0 + r0) * H + c0];
    bS1 = &Wt[(size_t)(j0 + r1) * H + c1];
  }

  #define STAGE(bufsel, kOff)                                                   \
    do {                                                                        \
      char* _b = (char*)smem + (bufsel) * 32768;                                \
      __builtin_amdgcn_global_load_lds((const AS1 void*)(aS0 + (kOff)),         \
        (AS3 void*)(_b + tid * 16), 16, 0, 0);                                  \
      __builtin_amdgcn_global_load_lds((const AS1 void*)(aS1 + (kOff)),         \
        (AS3 void*)(_b + 8192 + tid * 16), 16, 0, 0);                           \
      __builtin_amdgcn_global_load_lds((const AS1 void*)(bS0 + (kOff)),         \
        (AS3 void*)(_b + 16384 + tid * 16), 16, 0, 0);                          \
      __builtin_amdgcn_global_load_lds((const AS1 void*)(bS1 + (kOff)),         \
        (AS3 void*)(_b + 24576 + tid * 16), 16, 0, 0);                          \
    } while (0)

  // Fragment read offsets (forward swizzle; r10-verified conflict-free).
  // A logical row R = wr*128 + mi*16 + l16 -> byte wr*8192 + mi*1024 +
  // (l16>>1)*128 + slot*16 ; B: wc*4096 + ni*1024 + same lane term.
  const int slot  = (4 * (l16 & 1) + lq) ^ ((l16 >> 1) & 7);
  const int laneT = (l16 >> 1) * 128 + slot * 16;
  const int aBase = wr * 8192 + laneT;
  const int bBase = wc * 4096 + laneT;

  f32x4 acc[8][4] = {};

  const int nsteps = H >> 5;                        // BK = 32
  STAGE(0, 0);
  __syncthreads();                                  // prologue DMA landed
  for (int t = 0; t < nsteps; ++t) {
    if (t + 1 < nsteps) STAGE((t + 1) & 1, (t + 1) * 32);
    const char* Ab = (const char*)smem + (t & 1) * 32768;
    const char* Bb = Ab + 16384;
    bf16x8 bfr[4];
    #pragma unroll
    for (int ni = 0; ni < 4; ++ni)
      bfr[ni] = *(const bf16x8*)(Bb + bBase + ni * 1024);
    #pragma unroll
    for (int mi = 0; mi < 8; ++mi) {
      bf16x8 af = *(const bf16x8*)(Ab + aBase + mi * 1024);
      #pragma unroll
      for (int ni = 0; ni < 4; ++ni)
        acc[mi][ni] = __builtin_amdgcn_mfma_f32_16x16x32_bf16(af, bfr[ni], acc[mi][ni], 0, 0, 0);
    }
    __syncthreads();   // vmcnt(0)+barrier: tile t+1 landed, buf t released
  }
  #undef STAGE

  // ---- epilogue: per-wave LDS transpose then coalesced f32x4 IO ----
  // C/D fragment layout: col = l16, row = lq*4 + r  [m89-verified]
  float* ep = Es + wave * (16 * EPAD);
  const int rr = lane >> 2;           // 0..15
  const int cq = (lane & 3) * 16;     // 0,16,32,48
  #pragma unroll
  for (int mi = 0; mi < 8; ++mi) {
    #pragma unroll
    for (int ni = 0; ni < 4; ++ni)
      #pragma unroll
      for (int r = 0; r < 4; ++r)
        ep[(lq * 4 + r) * EPAD + ni * 16 + l16] = acc[mi][ni][r];
    // same-wave ds_write -> ds_read: in-order LDS pipe, compiler waits lgkmcnt.
    const int i  = i0 + wr * 128 + mi * 16 + rr;
    const int jb = j0 + wc * 64 + cq;
    float* orow = &out[(size_t)i * H + jb];
    const unsigned short* grow = &g[(size_t)i * H + jb];
    #pragma unroll
    for (int t = 0; t < 4; ++t) {
      f32x4 a = *(const f32x4*)&ep[rr * EPAD + cq + 4 * t];
      bf16x4v gv = *(const bf16x4v*)&grow[4 * t];
      f32x4 o;
      #pragma unroll
      for (int e = 0; e < 4; ++e) o[e] = S * (a[e] + bf2f(gv[e]));
      *(f32x4*)&orow[4 * t] = o;
    }
  }
}

// ---- fallback GEMM (round-6 structure, 256 thr) for small-ws / odd-shape ----
template <int MODE>   // 1: xb staging + trig epi ; 2: f32 staging + trig epi
__global__ __launch_bounds__(256, 2)
void gemm_fb(const float* __restrict__ x, const unsigned short* __restrict__ xb,
             const unsigned short* __restrict__ Wt,
             const float* __restrict__ bv, const float* __restrict__ cv,
             const float* __restrict__ dv, float* __restrict__ out,
             float S, int H) {
  __shared__ unsigned char smem[36864];
  unsigned short* As = (unsigned short*)smem;            // [128][72]
  unsigned short* Bs = As + 128 * 72;
  float*          Es = (float*)smem;

  const int tid  = threadIdx.x;
  const int nwg  = gridDim.x;
  const int work = (nwg % 8 == 0) ? (blockIdx.x & 7) * (nwg >> 3) + (blockIdx.x >> 3)
                                  : blockIdx.x;
  const int nbj  = H / 128;
  const int bj   = work % nbj;
  const int bi   = work / nbj;
  const int i0   = bi * 128, j0 = bj * 128;
  const int wave = tid >> 6, lane = tid & 63;
  const int wr = wave >> 1, wc = wave & 1;
  const int l16 = lane & 15, lq = lane >> 4;

  f32x4 acc[4][4] = {};
  for (int kk = 0; kk < H; kk += 64) {
    if constexpr (MODE == 1) {
      #pragma unroll
      for (int it = 0; it < 4; ++it) {
        int q = it * 256 + tid;
        int r = q >> 3, c8 = (q & 7) << 3;
        *(bf16x8*)&As[r * 72 + c8] = *(const bf16x8*)&xb[(size_t)(i0 + r) * H + kk + c8];
      }
    } else {
      #pragma unroll
      for (int it = 0; it < 8; ++it) {
        int q = it * 256 + tid;
        int r = q >> 4, c4 = (q & 15) << 2;
        f32x4 v = *(const f32x4*)&x[(size_t)(i0 + r) * H + kk + c4];
        bf16x4v o;
        #pragma unroll
        for (int j = 0; j < 4; ++j) o[j] = (short)f2bf(v[j]);
        *(bf16x4v*)&As[r * 72 + c4] = o;
      }
    }
    #pragma unroll
    for (int it = 0; it < 4; ++it) {
      int q = it * 256 + tid;
      int r = q >> 3, c8 = (q & 7) << 3;
      *(bf16x8*)&Bs[r * 72 + c8] = *(const bf16x8*)&Wt[(size_t)(j0 + r) * H + kk + c8];
    }
    __syncthreads();
    #pragma unroll
    for (int s = 0; s < 2; ++s) {
      bf16x8 af[4], bfr[4];
      #pragma unroll
      for (int mi = 0; mi < 4; ++mi)
        af[mi] = *(const bf16x8*)&As[(wr * 64 + mi * 16 + l16) * 72 + s * 32 + lq * 8];
      #pragma unroll
      for (int ni = 0; ni < 4; ++ni)
        bfr[ni] = *(const bf16x8*)&Bs[(wc * 64 + ni * 16 + l16) * 72 + s * 32 + lq * 8];
      #pragma unroll
      for (int mi = 0; mi < 4; ++mi)
        #pragma unroll
        for (int ni = 0; ni < 4; ++ni)
          acc[mi][ni] = __builtin_amdgcn_mfma_f32_16x16x32_bf16(af[mi], bfr[ni], acc[mi][ni], 0, 0, 0);
    }
    __syncthreads();
  }
  float* ep = Es + wave * (16 * EPAD);
  const int rr = lane >> 2;
  const int cq = (lane & 3) * 16;
  #pragma unroll
  for (int mi = 0; mi < 4; ++mi) {
    #pragma unroll
    for (int ni = 0; ni < 4; ++ni)
      #pragma unroll
      for (int r = 0; r < 4; ++r)
        ep[(lq * 4 + r) * EPAD + ni * 16 + l16] = acc[mi][ni][r];
    const int i  = i0 + wr * 64 + mi * 16 + rr;
    const int jb = j0 + wc * 64 + cq;
    const float* xrow = &x[(size_t)i * H + jb];
    float*       orow = &out[(size_t)i * H + jb];
    #pragma unroll
    for (int t = 0; t < 4; ++t) {
      f32x4 a  = *(const f32x4*)&ep[rr * EPAD + cq + 4 * t];
      f32x4 xv = *(const f32x4*)&xrow[4 * t];
      f32x4 b4 = *(const f32x4*)&bv[jb + 4 * t];
      f32x4 c4 = *(const f32x4*)&cv[jb + 4 * t];
      f32x4 d4 = *(const f32x4*)&dv[jb + 4 * t];
      f32x4 o;
      #pragma unroll
      for (int e = 0; e < 4; ++e) {
        float s, co;
        my_sincos(xv[e], s, co);
        const float tanv = s * __builtin_amdgcn_rcpf(co);
        o[e] = S * (fmaf(b4[e], s, a[e]) + fmaf(c4[e], co, d4[e] * tanv));
      }
      *(f32x4*)&orow[4 * t] = o;
    }
  }
}

extern "C" void kernel_launch(void* const* d_in, const int* in_sizes, int n_in,
                              void* d_out, int out_size, void* d_ws, size_t ws_size,
                              hipStream_t stream) {
  const float* x = (const float*)d_in[0];
  const float* W = (const float*)d_in[1];
  const float* b = (const float*)d_in[2];
  const float* c = (const float*)d_in[3];
  const float* d = (const float*)d_in[4];
  float* out = (float*)d_out;
  const int H = in_sizes[2];          // 1024
  const int M = in_sizes[0] / H;      // 16384

  // Scalar RK4 factor: y_final = S * z (ODE linear in y, y0 = 0).
  const int NT = 100;
  float ts[NT];
  const float step = (float)(1.0 / 99.0);
  for (int i = 0; i < NT; ++i) ts[i] = (float)i * step;
  ts[NT - 1] = 1.0f;
  double yy = 0.0;
  for (int i = 0; i < NT - 1; ++i) {
    const double t = (double)ts[i], dt = (double)(ts[i + 1] - ts[i]);
    const double k1 = t - yy;
    const double k2 = (t + 0.5 * dt) - (yy + 0.5 * dt * k1);
    const double k3 = (t + 0.5 * dt) - (yy + 0.5 * dt * k2);
    const double k4 = (t + dt) - (yy + dt * k3);
    yy += dt / 6.0 * (k1 + 2.0 * k2 + 2.0 * k3 + k4);
  }
  const float S = (float)yy;

  unsigned short* Wt = (unsigned short*)d_ws;                 // 2 MB bf16 W^T
  unsigned short* xb = Wt + (size_t)H * H;                    // 32 MB bf16 x
  unsigned short* g  = xb + (size_t)M * H;                    // 32 MB bf16 g
  const size_t needW  = (size_t)H * H * 2;
  const size_t needXb = (size_t)M * H * 2;
  const int n4 = M * H / 4;

  const int nblk256 = (M / 256) * (H / 256);
  const bool shapeOK = (H % 256 == 0) && (M % 256 == 0) && (nblk256 % 8 == 0);

  if (ws_size >= needW + 2 * needXb && shapeOK) {
    prep_all<<<256 + 2048, 256, 0, stream>>>(W, x, b, c, d, Wt, xb, g, H, n4);
    gemm_256<<<nblk256, 512, 0, stream>>>(xb, Wt, g, out, S, H);
  } else if (ws_size >= needW + needXb) {
    dim3 tgrid(H / 64, H / 64);
    transpose_W<<<tgrid, 256, 0, stream>>>(W, Wt, H);
    cvt_x<<<2048, 256, 0, stream>>>(x, xb, n4);
    gemm_fb<1><<<(H / 128) * (M / 128), 256, 0, stream>>>(x, xb, Wt, b, c, d, out, S, H);
  } else {
    dim3 tgrid(H / 64, H / 64);
    transpose_W<<<tgrid, 256, 0, stream>>>(W, Wt, H);
    gemm_fb<2><<<(H / 128) * (M / 128), 256, 0, stream>>>(x, nullptr, Wt, b, c, d, out, S, H);
  }
}

// Round 14
// 81.297 us; speedup vs baseline: 1.3884x; 1.0066x over previous
//
#include <hip/hip_runtime.h>
#include <hip/hip_bf16.h>

typedef __attribute__((ext_vector_type(4))) float  f32x4;
typedef __attribute__((ext_vector_type(8))) short  bf16x8;
typedef __attribute__((ext_vector_type(4))) short  bf16x4v;

#define EPAD 68   // f32 elems per epilogue LDS row
#define AS1 __attribute__((address_space(1)))
#define AS3 __attribute__((address_space(3)))

__device__ __forceinline__ unsigned short f2bf(float f) {
  __hip_bfloat16 h = __float2bfloat16(f);
  unsigned short u; __builtin_memcpy(&u, &h, 2); return u;
}
__device__ __forceinline__ float bf2f(short u) {
  unsigned int w = ((unsigned int)(unsigned short)u) << 16;
  float f; __builtin_memcpy(&f, &w, 4); return f;
}

// Fully-inline sincos. k in f32 (|x|<=~6 -> k exact), reduction in f64
// (tan pole needs ABSOLUTE reduced-arg err < ~6e-9), polys f32.
__device__ __forceinline__ void my_sincos(float xf, float& s_out, float& c_out) {
  const float kf = __builtin_rintf(xf * 0.636619772367581343f);      // x * 2/pi
  const int   q  = (int)kf;
  const double kd = (double)kf;
  double rd = __builtin_fma(-kd, 1.5707963267948966,    (double)xf); // pio2_hi
  rd        = __builtin_fma(-kd, 6.123233995736766e-17, rd);         // pio2_lo
  const float r = (float)rd;
  const float z = r * r;
  const float ps = fmaf(z, fmaf(z, fmaf(z, 2.7183114939898219e-06f,
                                           -1.9839334836096632e-04f),
                                   8.3333293858894632e-03f),
                        -1.6666666641626524e-01f);
  const float sr = fmaf(r * z, ps, r);                               // sin(r)
  const float pc = fmaf(z, fmaf(z, fmaf(z, 2.4390448796277409e-05f,
                                           -1.3886763774609929e-03f),
                                   4.1666623323739063e-02f),
                        -4.9999999725103100e-01f);
  const float cr = fmaf(z, pc, 1.0f);                                // cos(r)
  const bool swap = (q & 1) != 0;
  float s1 = swap ? cr : sr;
  float c1 = swap ? sr : cr;
  if (q & 2)       s1 = -s1;
  if ((q + 1) & 2) c1 = -c1;
  s_out = s1; c_out = c1;
}

// ---- fused prep: blocks 0..255 transpose W -> Wt(bf16); blocks 256+ stream
// x -> xb(bf16) and g = b*sin(x)+c*cos(x)+d*tan(x) -> bf16 (trig hides under
// the memory-bound stream; measured at the BW floor ~22 us).
__global__ __launch_bounds__(256)
void prep_all(const float* __restrict__ W, const float* __restrict__ x,
              const float* __restrict__ bv, const float* __restrict__ cv,
              const float* __restrict__ dv,
              unsigned short* __restrict__ Wt, unsigned short* __restrict__ xb,
              unsigned short* __restrict__ g, int H, int n4) {
  __shared__ float tile[64][65];
  const int t = threadIdx.x;
  if (blockIdx.x < 256) {
    const int blk = blockIdx.x;
    const int n0 = (blk & 15) << 6;
    const int k0 = (blk >> 4) << 6;
    #pragma unroll
    for (int it = 0; it < 4; ++it) {
      int q = it * 256 + t;
      int r = q >> 4, c4 = (q & 15) << 2;
      f32x4 v = *(const f32x4*)&W[(size_t)(k0 + r) * H + n0 + c4];
      tile[r][c4 + 0] = v[0]; tile[r][c4 + 1] = v[1];
      tile[r][c4 + 2] = v[2]; tile[r][c4 + 3] = v[3];
    }
    __syncthreads();
    #pragma unroll
    for (int it = 0; it < 4; ++it) {
      int q = it * 256 + t;
      int r = q >> 4, c4 = (q & 15) << 2;
      bf16x4v o;
      #pragma unroll
      for (int j = 0; j < 4; ++j) o[j] = (short)f2bf(tile[c4 + j][r]);
      *(bf16x4v*)&Wt[(size_t)(n0 + r) * H + k0 + c4] = o;
    }
  } else {
    const int jm = (H >> 2) - 1;             // H pow2: chunk-index mask
    int i = (blockIdx.x - 256) * 256 + t;
    const int stride = ((int)gridDim.x - 256) * 256;
    for (; i < n4; i += stride) {
      f32x4 v = ((const f32x4*)x)[i];
      const int j4 = (i & jm) << 2;
      f32x4 b4 = *(const f32x4*)&bv[j4];
      f32x4 c4 = *(const f32x4*)&cv[j4];
      f32x4 d4 = *(const f32x4*)&dv[j4];
      bf16x4v xo, go;
      #pragma unroll
      for (int e = 0; e < 4; ++e) {
        xo[e] = (short)f2bf(v[e]);
        float s, co;
        my_sincos(v[e], s, co);
        const float tn = s * __builtin_amdgcn_rcpf(co);  // |err| ~0.13 @ pole
        go[e] = (short)f2bf(fmaf(b4[e], s, fmaf(c4[e], co, d4[e] * tn)));
      }
      ((bf16x4v*)xb)[i] = xo;
      ((bf16x4v*)g)[i]  = go;
    }
  }
}

// ---- fallback prep kernels ----
__global__ __launch_bounds__(256)
void transpose_W(const float* __restrict__ W, unsigned short* __restrict__ Wt, int H) {
  __shared__ float tile[64][65];
  const int k0 = blockIdx.y * 64;
  const int n0 = blockIdx.x * 64;
  const int t = threadIdx.x;
  #pragma unroll
  for (int it = 0; it < 4; ++it) {
    int q = it * 256 + t;
    int r = q >> 4, c4 = (q & 15) << 2;
    f32x4 v = *(const f32x4*)&W[(size_t)(k0 + r) * H + n0 + c4];
    tile[r][c4 + 0] = v[0]; tile[r][c4 + 1] = v[1];
    tile[r][c4 + 2] = v[2]; tile[r][c4 + 3] = v[3];
  }
  __syncthreads();
  #pragma unroll
  for (int it = 0; it < 4; ++it) {
    int q = it * 256 + t;
    int r = q >> 4, c4 = (q & 15) << 2;
    bf16x4v o;
    #pragma unroll
    for (int j = 0; j < 4; ++j) o[j] = (short)f2bf(tile[c4 + j][r]);
    *(bf16x4v*)&Wt[(size_t)(n0 + r) * H + k0 + c4] = o;
  }
}
__global__ __launch_bounds__(256)
void cvt_x(const float* __restrict__ x, unsigned short* __restrict__ xb, int n4) {
  int i = blockIdx.x * 256 + threadIdx.x;
  const int stride = gridDim.x * 256;
  for (; i < n4; i += stride) {
    f32x4 v = ((const f32x4*)x)[i];
    bf16x4v o;
    #pragma unroll
    for (int j = 0; j < 4; ++j) o[j] = (short)f2bf(v[j]);
    ((bf16x4v*)xb)[i] = o;
  }
}

// ---- main GEMM: 256x256 tile, 8 waves, counted-vmcnt async pipeline ----
// r13's structure (proven: 58us) with the K-loop sync replaced per T3/T4:
// 3 buffers, stage 2 tiles ahead, raw s_barrier pairs, vmcnt(8) steady state
// (never 0 until the tail). Correctness chain:
//   - leading barrier: each thread's vmcnt(8) retires its OWN stage(t)
//     issues; barrier publishes them to all waves -> tile t readable.
//   - trailing barrier: all MFMA consumers of tile t precede it (data in
//     regs via compiler lgkmcnt), so the NEXT iteration's STAGE may
//     overwrite buf t%3 = buf (t+3)%3 safely.
//   - memory-clobber asm fences stop ds_reads hoisting above the leading
//     barrier or sinking below the trailing one (rule #18 family).
// Swizzle unchanged (r10-verified: conflict-free + bijective). LDS 96KB ->
// 1 block/CU (r13 already ran 1). setprio(1) wraps the MFMA cluster (T5).
__global__ __launch_bounds__(512, 2)
void gemm_256(const unsigned short* __restrict__ xb,
              const unsigned short* __restrict__ Wt,
              const unsigned short* __restrict__ g,
              float* __restrict__ out, float S, int H) {
  __shared__ unsigned char smem[98304];             // 3 x 32KB K-tile buffers
  float* Es = (float*)smem;                         // epilogue overlay (34.8KB)

  const int tid  = threadIdx.x;
  const int nwg  = gridDim.x;
  const int work = (blockIdx.x & 7) * (nwg >> 3) + (blockIdx.x >> 3);
  const int nbj  = H >> 8;                          // N tiles of 256
  const int bj   = work % nbj;
  const int bi   = work / nbj;
  const int i0   = bi * 256, j0 = bj * 256;
  const int wave = tid >> 6, lane = tid & 63;
  const int wr   = wave >> 2, wc = wave & 3;        // 2(M) x 4(N) wave grid
  const int l16  = lane & 15, lq = lane >> 4;

  // Staging sources (inverse swizzle; r10-verified map). Thread issues 2 A
  // chunks + 2 B chunks of 16B: dest D = is*8192 + tid*16 within the region.
  const unsigned short *aS0, *aS1, *bS0, *bS1;
  {
    const int D0 = tid * 16,        sup0 = D0 >> 7;
    const int sl0 = ((D0 >> 4) & 7) ^ (sup0 & 7);
    const int r0  = sup0 * 2 + (sl0 >> 2), c0 = (sl0 & 3) << 3;
    const int D1 = 8192 + tid * 16, sup1 = D1 >> 7;
    const int sl1 = ((D1 >> 4) & 7) ^ (sup1 & 7);
    const int r1  = sup1 * 2 + (sl1 >> 2), c1 = (sl1 & 3) << 3;
    aS0 = &xb[(size_t)(i0 + r0) * H + c0];
    aS1 = &xb[(size_t)(i0 + r1) * H + c1];
    bS0 = &Wt[(size_t)(j0 + r0) * H + c0];
    bS1 = &Wt[(size_t)(j0 + r1) * H + c1];
  }

  #define STAGE(bufq, kOff)                                                     \
    do {                                                                        \
      char* _b = (char*)smem + (bufq) * 32768;                                  \
      __builtin_amdgcn_global_load_lds((const AS1 void*)(aS0 + (kOff)),         \
        (AS3 void*)(_b + tid * 16), 16, 0, 0);                                  \
      __builtin_amdgcn_global_load_lds((const AS1 void*)(aS1 + (kOff)),         \
        (AS3 void*)(_b + 8192 + tid * 16), 16, 0, 0);                           \
      __builtin_amdgcn_global_load_lds((const AS1 void*)(bS0 + (kOff)),         \
        (AS3 void*)(_b + 16384 + tid * 16), 16, 0, 0);                          \
      __builtin_amdgcn_global_load_lds((const AS1 void*)(bS1 + (kOff)),         \
        (AS3 void*)(_b + 24576 + tid * 16), 16, 0, 0);                          \
    } while (0)

  // Fragment read offsets (forward swizzle; r10-verified conflict-free).
  const int slot  = (4 * (l16 & 1) + lq) ^ ((l16 >> 1) & 7);
  const int laneT = (l16 >> 1) * 128 + slot * 16;
  const int aBase = wr * 8192 + laneT;
  const int bBase = wc * 4096 + laneT;

  f32x4 acc[8][4] = {};

  const int nsteps = H >> 5;                        // BK = 32
  STAGE(0, 0);
  STAGE(1, 32);
  int bufc = 0;                                     // buffer holding tile t
  for (int t = 0; t < nsteps; ++t) {
    if (t + 2 < nsteps) {
      int buf2 = bufc + 2; if (buf2 >= 3) buf2 -= 3;
      STAGE(buf2, (t + 2) * 32);
      asm volatile("s_waitcnt vmcnt(8)" ::: "memory");   // stage(t) retired
    } else if (t + 2 == nsteps) {
      asm volatile("s_waitcnt vmcnt(4)" ::: "memory");
    } else {
      asm volatile("s_waitcnt vmcnt(0)" ::: "memory");
    }
    __builtin_amdgcn_s_barrier();                   // publish tile t to all waves
    asm volatile("" ::: "memory");                  // no ds_read above this
    const char* Ab = (const char*)smem + bufc * 32768;
    const char* Bb = Ab + 16384;
    bf16x8 bfr[4];
    #pragma unroll
    for (int ni = 0; ni < 4; ++ni)
      bfr[ni] = *(const bf16x8*)(Bb + bBase + ni * 1024);
    __builtin_amdgcn_s_setprio(1);
    #pragma unroll
    for (int mi = 0; mi < 8; ++mi) {
      bf16x8 af = *(const bf16x8*)(Ab + aBase + mi * 1024);
      #pragma unroll
      for (int ni = 0; ni < 4; ++ni)
        acc[mi][ni] = __builtin_amdgcn_mfma_f32_16x16x32_bf16(af, bfr[ni], acc[mi][ni], 0, 0, 0);
    }
    __builtin_amdgcn_s_setprio(0);
    asm volatile("" ::: "memory");                  // reads done (consumed)
    __builtin_amdgcn_s_barrier();                   // license overwrite of bufc
    bufc += 1; if (bufc == 3) bufc = 0;
  }
  #undef STAGE
  __syncthreads();                                  // full drain before Es overlay

  // ---- epilogue: per-wave LDS transpose then coalesced f32x4 IO ----
  // C/D fragment layout: col = l16, row = lq*4 + r  [m89-verified]
  float* ep = Es + wave * (16 * EPAD);
  const int rr = lane >> 2;           // 0..15
  const int cq = (lane & 3) * 16;     // 0,16,32,48
  #pragma unroll
  for (int mi = 0; mi < 8; ++mi) {
    #pragma unroll
    for (int ni = 0; ni < 4; ++ni)
      #pragma unroll
      for (int r = 0; r < 4; ++r)
        ep[(lq * 4 + r) * EPAD + ni * 16 + l16] = acc[mi][ni][r];
    // same-wave ds_write -> ds_read: in-order LDS pipe, compiler waits lgkmcnt.
    const int i  = i0 + wr * 128 + mi * 16 + rr;
    const int jb = j0 + wc * 64 + cq;
    float* orow = &out[(size_t)i * H + jb];
    const unsigned short* grow = &g[(size_t)i * H + jb];
    #pragma unroll
    for (int t = 0; t < 4; ++t) {
      f32x4 a = *(const f32x4*)&ep[rr * EPAD + cq + 4 * t];
      bf16x4v gv = *(const bf16x4v*)&grow[4 * t];
      f32x4 o;
      #pragma unroll
      for (int e = 0; e < 4; ++e) o[e] = S * (a[e] + bf2f(gv[e]));
      *(f32x4*)&orow[4 * t] = o;
    }
  }
}

// ---- fallback GEMM (round-6 structure, 256 thr) for small-ws / odd-shape ----
template <int MODE>   // 1: xb staging + trig epi ; 2: f32 staging + trig epi
__global__ __launch_bounds__(256, 2)
void gemm_fb(const float* __restrict__ x, const unsigned short* __restrict__ xb,
             const unsigned short* __restrict__ Wt,
             const float* __restrict__ bv, const float* __restrict__ cv,
             const float* __restrict__ dv, float* __restrict__ out,
             float S, int H) {
  __shared__ unsigned char smem[36864];
  unsigned short* As = (unsigned short*)smem;            // [128][72]
  unsigned short* Bs = As + 128 * 72;
  float*          Es = (float*)smem;

  const int tid  = threadIdx.x;
  const int nwg  = gridDim.x;
  const int work = (nwg % 8 == 0) ? (blockIdx.x & 7) * (nwg >> 3) + (blockIdx.x >> 3)
                                  : blockIdx.x;
  const int nbj  = H / 128;
  const int bj   = work % nbj;
  const int bi   = work / nbj;
  const int i0   = bi * 128, j0 = bj * 128;
  const int wave = tid >> 6, lane = tid & 63;
  const int wr = wave >> 1, wc = wave & 1;
  const int l16 = lane & 15, lq = lane >> 4;

  f32x4 acc[4][4] = {};
  for (int kk = 0; kk < H; kk += 64) {
    if constexpr (MODE == 1) {
      #pragma unroll
      for (int it = 0; it < 4; ++it) {
        int q = it * 256 + tid;
        int r = q >> 3, c8 = (q & 7) << 3;
        *(bf16x8*)&As[r * 72 + c8] = *(const bf16x8*)&xb[(size_t)(i0 + r) * H + kk + c8];
      }
    } else {
      #pragma unroll
      for (int it = 0; it < 8; ++it) {
        int q = it * 256 + tid;
        int r = q >> 4, c4 = (q & 15) << 2;
        f32x4 v = *(const f32x4*)&x[(size_t)(i0 + r) * H + kk + c4];
        bf16x4v o;
        #pragma unroll
        for (int j = 0; j < 4; ++j) o[j] = (short)f2bf(v[j]);
        *(bf16x4v*)&As[r * 72 + c4] = o;
      }
    }
    #pragma unroll
    for (int it = 0; it < 4; ++it) {
      int q = it * 256 + tid;
      int r = q >> 3, c8 = (q & 7) << 3;
      *(bf16x8*)&Bs[r * 72 + c8] = *(const bf16x8*)&Wt[(size_t)(j0 + r) * H + kk + c8];
    }
    __syncthreads();
    #pragma unroll
    for (int s = 0; s < 2; ++s) {
      bf16x8 af[4], bfr[4];
      #pragma unroll
      for (int mi = 0; mi < 4; ++mi)
        af[mi] = *(const bf16x8*)&As[(wr * 64 + mi * 16 + l16) * 72 + s * 32 + lq * 8];
      #pragma unroll
      for (int ni = 0; ni < 4; ++ni)
        bfr[ni] = *(const bf16x8*)&Bs[(wc * 64 + ni * 16 + l16) * 72 + s * 32 + lq * 8];
      #pragma unroll
      for (int mi = 0; mi < 4; ++mi)
        #pragma unroll
        for (int ni = 0; ni < 4; ++ni)
          acc[mi][ni] = __builtin_amdgcn_mfma_f32_16x16x32_bf16(af[mi], bfr[ni], acc[mi][ni], 0, 0, 0);
    }
    __syncthreads();
  }
  float* ep = Es + wave * (16 * EPAD);
  const int rr = lane >> 2;
  const int cq = (lane & 3) * 16;
  #pragma unroll
  for (int mi = 0; mi < 4; ++mi) {
    #pragma unroll
    for (int ni = 0; ni < 4; ++ni)
      #pragma unroll
      for (int r = 0; r < 4; ++r)
        ep[(lq * 4 + r) * EPAD + ni * 16 + l16] = acc[mi][ni][r];
    const int i  = i0 + wr * 64 + mi * 16 + rr;
    const int jb = j0 + wc * 64 + cq;
    const float* xrow = &x[(size_t)i * H + jb];
    float*       orow = &out[(size_t)i * H + jb];
    #pragma unroll
    for (int t = 0; t < 4; ++t) {
      f32x4 a  = *(const f32x4*)&ep[rr * EPAD + cq + 4 * t];
      f32x4 xv = *(const f32x4*)&xrow[4 * t];
      f32x4 b4 = *(const f32x4*)&bv[jb + 4 * t];
      f32x4 c4 = *(const f32x4*)&cv[jb + 4 * t];
      f32x4 d4 = *(const f32x4*)&dv[jb + 4 * t];
      f32x4 o;
      #pragma unroll
      for (int e = 0; e < 4; ++e) {
        float s, co;
        my_sincos(xv[e], s, co);
        const float tanv = s * __builtin_amdgcn_rcpf(co);
        o[e] = S * (fmaf(b4[e], s, a[e]) + fmaf(c4[e], co, d4[e] * tanv));
      }
      *(f32x4*)&orow[4 * t] = o;
    }
  }
}

extern "C" void kernel_launch(void* const* d_in, const int* in_sizes, int n_in,
                              void* d_out, int out_size, void* d_ws, size_t ws_size,
                              hipStream_t stream) {
  const float* x = (const float*)d_in[0];
  const float* W = (const float*)d_in[1];
  const float* b = (const float*)d_in[2];
  const float* c = (const float*)d_in[3];
  const float* d = (const float*)d_in[4];
  float* out = (float*)d_out;
  const int H = in_sizes[2];          // 1024
  const int M = in_sizes[0] / H;      // 16384

  // Scalar RK4 factor: y_final = S * z (ODE linear in y, y0 = 0).
  const int NT = 100;
  float ts[NT];
  const float step = (float)(1.0 / 99.0);
  for (int i = 0; i < NT; ++i) ts[i] = (float)i * step;
  ts[NT - 1] = 1.0f;
  double yy = 0.0;
  for (int i = 0; i < NT - 1; ++i) {
    const double t = (double)ts[i], dt = (double)(ts[i + 1] - ts[i]);
    const double k1 = t - yy;
    const double k2 = (t + 0.5 * dt) - (yy + 0.5 * dt * k1);
    const double k3 = (t + 0.5 * dt) - (yy + 0.5 * dt * k2);
    const double k4 = (t + dt) - (yy + dt * k3);
    yy += dt / 6.0 * (k1 + 2.0 * k2 + 2.0 * k3 + k4);
  }
  const float S = (float)yy;

  unsigned short* Wt = (unsigned short*)d_ws;                 // 2 MB bf16 W^T
  unsigned short* xb = Wt + (size_t)H * H;                    // 32 MB bf16 x
  unsigned short* g  = xb + (size_t)M * H;                    // 32 MB bf16 g
  const size_t needW  = (size_t)H * H * 2;
  const size_t needXb = (size_t)M * H * 2;
  const int n4 = M * H / 4;

  const int nblk256 = (M / 256) * (H / 256);
  const bool shapeOK = (H % 256 == 0) && (M % 256 == 0) && (nblk256 % 8 == 0)
                    && ((H >> 5) >= 3);   // pipeline needs >= 3 K-steps

  if (ws_size >= needW + 2 * needXb && shapeOK) {
    prep_all<<<256 + 2048, 256, 0, stream>>>(W, x, b, c, d, Wt, xb, g, H, n4);
    gemm_256<<<nblk256, 512, 0, stream>>>(xb, Wt, g, out, S, H);
  } else if (ws_size >= needW + needXb) {
    dim3 tgrid(H / 64, H / 64);
    transpose_W<<<tgrid, 256, 0, stream>>>(W, Wt, H);
    cvt_x<<<2048, 256, 0, stream>>>(x, xb, n4);
    gemm_fb<1><<<(H / 128) * (M / 128), 256, 0, stream>>>(x, xb, Wt, b, c, d, out, S, H);
  } else {
    dim3 tgrid(H / 64, H / 64);
    transpose_W<<<tgrid, 256, 0, stream>>>(W, Wt, H);
    gemm_fb<2><<<(H / 128) * (M / 128), 256, 0, stream>>>(x, nullptr, Wt, b, c, d, out, S, H);
  }
}